// Round 2
// baseline (16765.982 us; speedup 1.0000x reference)
//
#include <hip/hip_runtime.h>

using u16 = unsigned short;

constexpr int CIN = 16, COUT = 32, COFF = 16;
constexpr int D = 32, H = 128, W = 160;
constexpr int HW = H * W;         // 20480
constexpr int DHW = D * HW;       // 655360
constexpr int NOUT = COUT * DHW;  // 20971520
constexpr float EPS = 1e-5f;

// ---- workspace layout (byte offsets) ----
// [0, 16384)      : 4096 x 4B slots, table S (floats; slot 3000 = dtype flag int)
//   S[0..1023]    scale1 per (c*D+d)       S[1024..2047] bias1
//   S[2048..2079] sum2   S[2080..2111] sumsq2
//   S[2112..2143] sumd   S[2144..2175] sumsqd
//   S[2176..2207] s2     S[2208..2239] o2
//   S[2240..2271] sd     S[2272..2303] od
// [16384, 262144) : fp32 canonical weights WF (48864 floats used)
// [262144, 42205184) : a1 bf16[NOUT]  (deform raw -> normalized in place)
constexpr size_t WF_OFF = 16384;
constexpr size_t A1_OFF = 262144;
constexpr int WOFF_O = 0, WREG_O = 2592, W2_O = 7200, WD_O = 34848;
constexpr int G1_O = 48672, B1_O = 48704, G2_O = 48736, B2_O = 48768, GD_O = 48800, BD_O = 48832;
constexpr int FLAG_SLOT = 3000;

static __device__ __forceinline__ float bf2f(u16 h) {
  unsigned u = ((unsigned)h) << 16;
  float f;
  __builtin_memcpy(&f, &u, 4);
  return f;
}
static __device__ __forceinline__ u16 f2bf(float f) {
  unsigned u;
  __builtin_memcpy(&u, &f, 4);
  u += 0x7fffu + ((u >> 16) & 1u);
  return (u16)(u >> 16);
}
// dual-dtype input load: bf==1 -> data is bf16, else fp32
static __device__ __forceinline__ float ldin(const void* p, int i, int bf) {
  float r;
  if (bf) r = bf2f(((const u16*)p)[i]);
  else r = ((const float*)p)[i];
  return r;
}

__global__ __launch_bounds__(256) void zero_kernel(float* __restrict__ S) {
  S[blockIdx.x * 256 + threadIdx.x] = 0.f;
}

// decide input dtype from first 4096 u16 words of x
__global__ __launch_bounds__(256) void sniff_kernel(const u16* __restrict__ x, int* __restrict__ flag) {
  __shared__ int sh[256];
  int cnt = 0;
  for (int i = threadIdx.x; i < 4096; i += 256) {
    int e = (x[i] >> 7) & 0xff;
    cnt += (e >= 96 && e <= 144) ? 1 : 0;
  }
  sh[threadIdx.x] = cnt;
  __syncthreads();
  for (int s = 128; s > 0; s >>= 1) {
    if (threadIdx.x < (unsigned)s) sh[threadIdx.x] += sh[threadIdx.x + s];
    __syncthreads();
  }
  if (threadIdx.x == 0) flag[0] = (sh[0] > 3072) ? 1 : 0;
}

__global__ __launch_bounds__(256) void cvt_kernel(const void* __restrict__ in,
                                                  float* __restrict__ out, int n,
                                                  const int* __restrict__ flagp) {
  int bf = flagp[0];
  int i = blockIdx.x * 256 + threadIdx.x;
  if (i < n) out[i] = ldin(in, i, bf);
}

// Deformable conv: one thread per (d, y, x).
__global__ __launch_bounds__(256) void deform_kernel(const void* __restrict__ x,
                                                     const void* __restrict__ f,
                                                     const float* __restrict__ w_off_f,
                                                     const float* __restrict__ w_reg_f,
                                                     u16* __restrict__ a1,
                                                     const int* __restrict__ flagp) {
  const int bf = flagp[0];
  const int bid = blockIdx.x;
  const int d = bid / (HW / 256);
  const int p = (bid % (HW / 256)) * 256 + threadIdx.x;
  const int y = p / W;
  const int xx = p % W;

  float doff[18];
#pragma unroll
  for (int t = 0; t < 18; t++) doff[t] = 0.f;
  for (int ci = 0; ci < COFF; ci++) {
    const int fbase = ci * DHW + d * HW;
#pragma unroll
    for (int ki = 0; ki < 3; ki++) {
      int yy = y - 1 + ki;
      bool yok = (unsigned)yy < (unsigned)H;
#pragma unroll
      for (int kj = 0; kj < 3; kj++) {
        int xj = xx - 1 + kj;
        float v = (yok && (unsigned)xj < (unsigned)W) ? ldin(f, fbase + yy * W + xj, bf) : 0.f;
        int widx = ci * 9 + ki * 3 + kj;
#pragma unroll
        for (int t = 0; t < 18; t++) doff[t] += v * w_off_f[t * 144 + widx];
      }
    }
  }

  float acc[COUT];
#pragma unroll
  for (int co = 0; co < COUT; co++) acc[co] = 0.f;

#pragma unroll
  for (int t = 0; t < 9; t++) {
    float dy = fminf(fmaxf(doff[2 * t], -1.f), 1.f);
    float dx = fminf(fmaxf(doff[2 * t + 1], -1.f), 1.f);
    float py = (float)(y - 1 + t / 3) + dy;
    float px = (float)(xx - 1 + t % 3) + dx;
    float y0f = floorf(py), x0f = floorf(px);
    float wy1 = py - y0f, wx1 = px - x0f;
    int y0 = (int)y0f, x0i = (int)x0f;
    int y1 = y0 + 1, x1 = x0i + 1;
    bool y0v = (unsigned)y0 < (unsigned)H, y1v = (unsigned)y1 < (unsigned)H;
    bool x0v = (unsigned)x0i < (unsigned)W, x1v = (unsigned)x1 < (unsigned)W;
    float c00 = (y0v && x0v) ? (1.f - wy1) * (1.f - wx1) : 0.f;
    float c01 = (y0v && x1v) ? (1.f - wy1) * wx1 : 0.f;
    float c10 = (y1v && x0v) ? wy1 * (1.f - wx1) : 0.f;
    float c11 = (y1v && x1v) ? wy1 * wx1 : 0.f;
    int y0c = min(max(y0, 0), H - 1) * W, y1c = min(max(y1, 0), H - 1) * W;
    int x0c = min(max(x0i, 0), W - 1), x1c = min(max(x1, 0), W - 1);

    for (int ci = 0; ci < CIN; ci++) {
      const int xbase = ci * DHW + d * HW;
      float s = c00 * ldin(x, xbase + y0c + x0c, bf) + c01 * ldin(x, xbase + y0c + x1c, bf) +
                c10 * ldin(x, xbase + y1c + x0c, bf) + c11 * ldin(x, xbase + y1c + x1c, bf);
#pragma unroll
      for (int co = 0; co < COUT; co++) acc[co] += s * w_reg_f[co * 144 + ci * 9 + t];
    }
  }

#pragma unroll
  for (int co = 0; co < COUT; co++) a1[co * DHW + d * HW + p] = f2bf(acc[co]);
}

// BN2d stats per (channel, slice)
__global__ __launch_bounds__(256) void bn1_stats_kernel(const u16* __restrict__ a1,
                                                        const float* __restrict__ g1f,
                                                        const float* __restrict__ b1f,
                                                        float* __restrict__ S) {
  int cd = blockIdx.x;
  int c = cd / D;
  const u16* p = a1 + (size_t)cd * HW;
  float sum = 0.f, sq = 0.f;
  for (int i = threadIdx.x; i < HW; i += 256) {
    float v = bf2f(p[i]);
    sum += v;
    sq += v * v;
  }
  __shared__ float sh[512];
  sh[threadIdx.x] = sum;
  sh[256 + threadIdx.x] = sq;
  __syncthreads();
  for (int s = 128; s > 0; s >>= 1) {
    if (threadIdx.x < (unsigned)s) {
      sh[threadIdx.x] += sh[threadIdx.x + s];
      sh[256 + threadIdx.x] += sh[256 + threadIdx.x + s];
    }
    __syncthreads();
  }
  if (threadIdx.x == 0) {
    float mean = sh[0] / (float)HW;
    float var = sh[256] / (float)HW - mean * mean;
    float sc = g1f[c] * rsqrtf(var + EPS);
    S[cd] = sc;
    S[1024 + cd] = b1f[c] - mean * sc;
  }
}

__global__ __launch_bounds__(256) void bn1_apply_kernel(u16* __restrict__ a1,
                                                        const float* __restrict__ S) {
  int i = (blockIdx.x * 256 + threadIdx.x) * 4;
  int cd = i / HW;
  float sc = S[cd], of = S[1024 + cd];
  ushort4 v = *(const ushort4*)(a1 + i);
  ushort4 r;
  r.x = f2bf(fmaxf(bf2f(v.x) * sc + of, 0.f));
  r.y = f2bf(fmaxf(bf2f(v.y) * sc + of, 0.f));
  r.z = f2bf(fmaxf(bf2f(v.z) * sc + of, 0.f));
  r.w = f2bf(fmaxf(bf2f(v.w) * sc + of, 0.f));
  *(ushort4*)(a1 + i) = r;
}

// conv3d 3x3x3 pad1, stats only (sum/sumsq per output channel), nothing stored
__global__ __launch_bounds__(256) void conv_stats_kernel(const void* __restrict__ in,
                                                         const float* __restrict__ wt, int nci,
                                                         int force_bf, const int* __restrict__ flagp,
                                                         float* __restrict__ sum,
                                                         float* __restrict__ sq) {
  const int bf = force_bf ? 1 : flagp[0];
  const int bid = blockIdx.x;
  const int co = bid / (D * 20);
  const int rem = bid % (D * 20);
  const int d = rem / 20;
  const int p = (rem % 20) * 256 + threadIdx.x;
  const int y = p / 40;
  const int x0 = (p % 40) * 4;

  float a0 = 0.f, a1v = 0.f, a2 = 0.f, a3 = 0.f;
  for (int ci = 0; ci < nci; ci++) {
#pragma unroll
    for (int kd = 0; kd < 3; kd++) {
      int dd = d - 1 + kd;
      if ((unsigned)dd >= (unsigned)D) continue;
      const int base = ci * DHW + dd * HW;
#pragma unroll
      for (int ky = 0; ky < 3; ky++) {
        int yy = y - 1 + ky;
        if ((unsigned)yy >= (unsigned)H) continue;
        const int rbase = base + yy * W;
        float r[6];
#pragma unroll
        for (int j = 0; j < 6; j++) {
          int xj = x0 - 1 + j;
          r[j] = ((unsigned)xj < (unsigned)W) ? ldin(in, rbase + xj, bf) : 0.f;
        }
        const float* wp = wt + (((co * nci + ci) * 3 + kd) * 3 + ky) * 3;
        float w0 = wp[0], w1 = wp[1], w2 = wp[2];
        a0 += r[0] * w0 + r[1] * w1 + r[2] * w2;
        a1v += r[1] * w0 + r[2] * w1 + r[3] * w2;
        a2 += r[2] * w0 + r[3] * w1 + r[4] * w2;
        a3 += r[3] * w0 + r[4] * w1 + r[5] * w2;
      }
    }
  }
  float ps = a0 + a1v + a2 + a3;
  float pq = a0 * a0 + a1v * a1v + a2 * a2 + a3 * a3;
  __shared__ float sh[512];
  sh[threadIdx.x] = ps;
  sh[256 + threadIdx.x] = pq;
  __syncthreads();
  for (int s = 128; s > 0; s >>= 1) {
    if (threadIdx.x < (unsigned)s) {
      sh[threadIdx.x] += sh[threadIdx.x + s];
      sh[256 + threadIdx.x] += sh[256 + threadIdx.x + s];
    }
    __syncthreads();
  }
  if (threadIdx.x == 0) {
    atomicAdd(&sum[co], sh[0]);
    atomicAdd(&sq[co], sh[256]);
  }
}

__global__ void bn3_final_kernel(float* __restrict__ S, const float* __restrict__ g2f,
                                 const float* __restrict__ b2f, const float* __restrict__ gdf,
                                 const float* __restrict__ bdf) {
  int t = threadIdx.x;  // 64 threads
  if (t < 32) {
    float mean = S[2048 + t] / (float)DHW;
    float var = S[2080 + t] / (float)DHW - mean * mean;
    float sc = g2f[t] * rsqrtf(var + EPS);
    S[2176 + t] = sc;
    S[2208 + t] = b2f[t] - mean * sc;
  } else {
    int c = t - 32;
    float mean = S[2112 + c] / (float)DHW;
    float var = S[2144 + c] / (float)DHW - mean * mean;
    float sc = gdf[c] * rsqrtf(var + EPS);
    S[2240 + c] = sc;
    S[2272 + c] = bdf[c] - mean * sc;
  }
}

// recompute both convs, fuse BN3 + add + relu, write d_out
__global__ __launch_bounds__(256) void final_conv_kernel(const u16* __restrict__ a1,
                                                         const void* __restrict__ x,
                                                         const float* __restrict__ w2f,
                                                         const float* __restrict__ wdf,
                                                         const float* __restrict__ S,
                                                         const int* __restrict__ flagp,
                                                         void* __restrict__ out) {
  const int bf = flagp[0];
  const int bid = blockIdx.x;
  const int co = bid / (D * 20);
  const int rem = bid % (D * 20);
  const int d = rem / 20;
  const int p = (rem % 20) * 256 + threadIdx.x;
  const int y = p / 40;
  const int x0 = (p % 40) * 4;

  float a0 = 0.f, a1v = 0.f, a2 = 0.f, a3 = 0.f;  // main conv (from a1, 32 ci)
  for (int ci = 0; ci < COUT; ci++) {
#pragma unroll
    for (int kd = 0; kd < 3; kd++) {
      int dd = d - 1 + kd;
      if ((unsigned)dd >= (unsigned)D) continue;
      const int base = ci * DHW + dd * HW;
#pragma unroll
      for (int ky = 0; ky < 3; ky++) {
        int yy = y - 1 + ky;
        if ((unsigned)yy >= (unsigned)H) continue;
        const u16* row = a1 + base + yy * W;
        float r[6];
#pragma unroll
        for (int j = 0; j < 6; j++) {
          int xj = x0 - 1 + j;
          r[j] = ((unsigned)xj < (unsigned)W) ? bf2f(row[xj]) : 0.f;
        }
        const float* wp = w2f + (((co * COUT + ci) * 3 + kd) * 3 + ky) * 3;
        float w0 = wp[0], w1 = wp[1], w2 = wp[2];
        a0 += r[0] * w0 + r[1] * w1 + r[2] * w2;
        a1v += r[1] * w0 + r[2] * w1 + r[3] * w2;
        a2 += r[2] * w0 + r[3] * w1 + r[4] * w2;
        a3 += r[3] * w0 + r[4] * w1 + r[5] * w2;
      }
    }
  }
  float b0 = 0.f, b1v = 0.f, b2v = 0.f, b3 = 0.f;  // identity conv (from x, 16 ci)
  for (int ci = 0; ci < CIN; ci++) {
#pragma unroll
    for (int kd = 0; kd < 3; kd++) {
      int dd = d - 1 + kd;
      if ((unsigned)dd >= (unsigned)D) continue;
      const int base = ci * DHW + dd * HW;
#pragma unroll
      for (int ky = 0; ky < 3; ky++) {
        int yy = y - 1 + ky;
        if ((unsigned)yy >= (unsigned)H) continue;
        const int rbase = base + yy * W;
        float r[6];
#pragma unroll
        for (int j = 0; j < 6; j++) {
          int xj = x0 - 1 + j;
          r[j] = ((unsigned)xj < (unsigned)W) ? ldin(x, rbase + xj, bf) : 0.f;
        }
        const float* wp = wdf + (((co * CIN + ci) * 3 + kd) * 3 + ky) * 3;
        float w0 = wp[0], w1 = wp[1], w2 = wp[2];
        b0 += r[0] * w0 + r[1] * w1 + r[2] * w2;
        b1v += r[1] * w0 + r[2] * w1 + r[3] * w2;
        b2v += r[2] * w0 + r[3] * w1 + r[4] * w2;
        b3 += r[3] * w0 + r[4] * w1 + r[5] * w2;
      }
    }
  }

  float s2 = S[2176 + co], o2 = S[2208 + co];
  float sd = S[2240 + co], od = S[2272 + co];
  float r0 = fmaxf(a0 * s2 + o2 + b0 * sd + od, 0.f);
  float r1 = fmaxf(a1v * s2 + o2 + b1v * sd + od, 0.f);
  float r2 = fmaxf(a2 * s2 + o2 + b2v * sd + od, 0.f);
  float r3 = fmaxf(a3 * s2 + o2 + b3 * sd + od, 0.f);
  int oi = co * DHW + d * HW + y * W + x0;
  if (bf) {
    ushort4 st;
    st.x = f2bf(r0);
    st.y = f2bf(r1);
    st.z = f2bf(r2);
    st.w = f2bf(r3);
    *(ushort4*)((u16*)out + oi) = st;
  } else {
    float4 st;
    st.x = r0;
    st.y = r1;
    st.z = r2;
    st.w = r3;
    *(float4*)((float*)out + oi) = st;
  }
}

extern "C" void kernel_launch(void* const* d_in, const int* in_sizes, int n_in,
                              void* d_out, int out_size, void* d_ws, size_t ws_size,
                              hipStream_t stream) {
  const void* x = d_in[0];
  const void* f = d_in[1];

  char* ws = (char*)d_ws;
  float* S = (float*)ws;
  int* flag = (int*)ws + FLAG_SLOT;
  float* WF = (float*)(ws + WF_OFF);
  u16* a1 = (u16*)(ws + A1_OFF);

  zero_kernel<<<16, 256, 0, stream>>>(S);
  sniff_kernel<<<1, 256, 0, stream>>>((const u16*)x, flag);

  const int cvt_n[10] = {2592, 4608, 27648, 13824, 32, 32, 32, 32, 32, 32};
  const int cvt_off[10] = {WOFF_O, WREG_O, W2_O, WD_O, G1_O, B1_O, G2_O, B2_O, GD_O, BD_O};
  const int cvt_in[10] = {2, 3, 6, 7, 8, 4, 5, 9, 10, 11};
  // careful mapping: inputs are x,f,w_off,w_reg,g1,b1,w2,g2,b2,wd,gd,bd
  const int src_idx[10] = {2, 3, 6, 9, 4, 5, 7, 8, 10, 11};
  for (int k = 0; k < 10; k++) {
    cvt_kernel<<<(cvt_n[k] + 255) / 256, 256, 0, stream>>>(d_in[src_idx[k]], WF + cvt_off[k],
                                                           cvt_n[k], flag);
  }
  (void)cvt_in;

  deform_kernel<<<D * (HW / 256), 256, 0, stream>>>(x, f, WF + WOFF_O, WF + WREG_O, a1, flag);

  bn1_stats_kernel<<<COUT * D, 256, 0, stream>>>(a1, WF + G1_O, WF + B1_O, S);
  bn1_apply_kernel<<<NOUT / 1024, 256, 0, stream>>>(a1, S);

  conv_stats_kernel<<<COUT * D * 20, 256, 0, stream>>>(a1, WF + W2_O, COUT, 1, flag, S + 2048,
                                                       S + 2080);
  conv_stats_kernel<<<COUT * D * 20, 256, 0, stream>>>(x, WF + WD_O, CIN, 0, flag, S + 2112,
                                                       S + 2144);
  bn3_final_kernel<<<1, 64, 0, stream>>>(S, WF + G2_O, WF + B2_O, WF + GD_O, WF + BD_O);

  final_conv_kernel<<<COUT * D * 20, 256, 0, stream>>>(a1, x, WF + W2_O, WF + WD_O, S, flag,
                                                       d_out);
}

// Round 6
// 7720.390 us; speedup vs baseline: 2.1716x; 2.1716x over previous
//
#include <hip/hip_runtime.h>

using u16 = unsigned short;

constexpr int CIN = 16, COUT = 32, COFF = 16;
constexpr int D = 32, H = 128, W = 160;
constexpr int HW = H * W;         // 20480
constexpr int DHW = D * HW;       // 655360
constexpr int NOUT = COUT * DHW;  // 20971520
constexpr float EPS = 1e-5f;

// ---- workspace layout (byte offsets) ---- (identical to the passing R2 build)
constexpr size_t WF_OFF = 16384;
constexpr size_t A1_OFF = 262144;
constexpr int WOFF_O = 0, WREG_O = 2592, W2_O = 7200, WD_O = 34848;
constexpr int G1_O = 48672, B1_O = 48704, G2_O = 48736, B2_O = 48768, GD_O = 48800, BD_O = 48832;
constexpr int FLAG_SLOT = 3000;

static __device__ __forceinline__ float bf2f(u16 h) {
  unsigned u = ((unsigned)h) << 16;
  float f;
  __builtin_memcpy(&f, &u, 4);
  return f;
}
static __device__ __forceinline__ u16 f2bf(float f) {
  unsigned u;
  __builtin_memcpy(&u, &f, 4);
  u += 0x7fffu + ((u >> 16) & 1u);
  return (u16)(u >> 16);
}
static __device__ __forceinline__ float ldin(const void* p, int i, int bf) {
  float r;
  if (bf) r = bf2f(((const u16*)p)[i]);
  else r = ((const float*)p)[i];
  return r;
}

__global__ __launch_bounds__(256) void zero_kernel(float* __restrict__ S) {
  S[blockIdx.x * 256 + threadIdx.x] = 0.f;
}

__global__ __launch_bounds__(256) void sniff_kernel(const u16* __restrict__ x,
                                                    int* __restrict__ flag) {
  __shared__ int sh[256];
  int cnt = 0;
  for (int i = threadIdx.x; i < 4096; i += 256) {
    int e = (x[i] >> 7) & 0xff;
    cnt += (e >= 96 && e <= 144) ? 1 : 0;
  }
  sh[threadIdx.x] = cnt;
  __syncthreads();
  for (int s = 128; s > 0; s >>= 1) {
    if (threadIdx.x < (unsigned)s) sh[threadIdx.x] += sh[threadIdx.x + s];
    __syncthreads();
  }
  if (threadIdx.x == 0) flag[0] = (sh[0] > 3072) ? 1 : 0;
}

__global__ __launch_bounds__(256) void cvt_kernel(const void* __restrict__ in,
                                                  float* __restrict__ out, int n,
                                                  const int* __restrict__ flagp) {
  int bf = flagp[0];
  int i = blockIdx.x * 256 + threadIdx.x;
  if (i < n) out[i] = ldin(in, i, bf);
}

// Deformable conv: one thread per (d, y, x).  (verbatim from the passing build)
__global__ __launch_bounds__(256) void deform_kernel(const void* __restrict__ x,
                                                     const void* __restrict__ f,
                                                     const float* __restrict__ w_off_f,
                                                     const float* __restrict__ w_reg_f,
                                                     u16* __restrict__ a1,
                                                     const int* __restrict__ flagp) {
  const int bf = flagp[0];
  const int bid = blockIdx.x;
  const int d = bid / (HW / 256);
  const int p = (bid % (HW / 256)) * 256 + threadIdx.x;
  const int y = p / W;
  const int xx = p % W;

  float doff[18];
#pragma unroll
  for (int t = 0; t < 18; t++) doff[t] = 0.f;
  for (int ci = 0; ci < COFF; ci++) {
    const int fbase = ci * DHW + d * HW;
#pragma unroll
    for (int ki = 0; ki < 3; ki++) {
      int yy = y - 1 + ki;
      bool yok = (unsigned)yy < (unsigned)H;
#pragma unroll
      for (int kj = 0; kj < 3; kj++) {
        int xj = xx - 1 + kj;
        float v = (yok && (unsigned)xj < (unsigned)W) ? ldin(f, fbase + yy * W + xj, bf) : 0.f;
        int widx = ci * 9 + ki * 3 + kj;
#pragma unroll
        for (int t = 0; t < 18; t++) doff[t] += v * w_off_f[t * 144 + widx];
      }
    }
  }

  float acc[COUT];
#pragma unroll
  for (int co = 0; co < COUT; co++) acc[co] = 0.f;

#pragma unroll
  for (int t = 0; t < 9; t++) {
    float dy = fminf(fmaxf(doff[2 * t], -1.f), 1.f);
    float dx = fminf(fmaxf(doff[2 * t + 1], -1.f), 1.f);
    float py = (float)(y - 1 + t / 3) + dy;
    float px = (float)(xx - 1 + t % 3) + dx;
    float y0f = floorf(py), x0f = floorf(px);
    float wy1 = py - y0f, wx1 = px - x0f;
    int y0 = (int)y0f, x0i = (int)x0f;
    int y1 = y0 + 1, x1 = x0i + 1;
    bool y0v = (unsigned)y0 < (unsigned)H, y1v = (unsigned)y1 < (unsigned)H;
    bool x0v = (unsigned)x0i < (unsigned)W, x1v = (unsigned)x1 < (unsigned)W;
    float c00 = (y0v && x0v) ? (1.f - wy1) * (1.f - wx1) : 0.f;
    float c01 = (y0v && x1v) ? (1.f - wy1) * wx1 : 0.f;
    float c10 = (y1v && x0v) ? wy1 * (1.f - wx1) : 0.f;
    float c11 = (y1v && x1v) ? wy1 * wx1 : 0.f;
    int y0c = min(max(y0, 0), H - 1) * W, y1c = min(max(y1, 0), H - 1) * W;
    int x0c = min(max(x0i, 0), W - 1), x1c = min(max(x1, 0), W - 1);

    for (int ci = 0; ci < CIN; ci++) {
      const int xbase = ci * DHW + d * HW;
      float s = c00 * ldin(x, xbase + y0c + x0c, bf) + c01 * ldin(x, xbase + y0c + x1c, bf) +
                c10 * ldin(x, xbase + y1c + x0c, bf) + c11 * ldin(x, xbase + y1c + x1c, bf);
#pragma unroll
      for (int co = 0; co < COUT; co++) acc[co] += s * w_reg_f[co * 144 + ci * 9 + t];
    }
  }

#pragma unroll
  for (int co = 0; co < COUT; co++) a1[co * DHW + d * HW + p] = f2bf(acc[co]);
}

__global__ __launch_bounds__(256) void bn1_stats_kernel(const u16* __restrict__ a1,
                                                        const float* __restrict__ g1f,
                                                        const float* __restrict__ b1f,
                                                        float* __restrict__ S) {
  int cd = blockIdx.x;
  int c = cd / D;
  const u16* p = a1 + (size_t)cd * HW;
  float sum = 0.f, sq = 0.f;
  for (int i = threadIdx.x; i < HW; i += 256) {
    float v = bf2f(p[i]);
    sum += v;
    sq += v * v;
  }
  __shared__ float sh[512];
  sh[threadIdx.x] = sum;
  sh[256 + threadIdx.x] = sq;
  __syncthreads();
  for (int s = 128; s > 0; s >>= 1) {
    if (threadIdx.x < (unsigned)s) {
      sh[threadIdx.x] += sh[threadIdx.x + s];
      sh[256 + threadIdx.x] += sh[256 + threadIdx.x + s];
    }
    __syncthreads();
  }
  if (threadIdx.x == 0) {
    float mean = sh[0] / (float)HW;
    float var = sh[256] / (float)HW - mean * mean;
    float sc = g1f[c] * rsqrtf(var + EPS);
    S[cd] = sc;
    S[1024 + cd] = b1f[c] - mean * sc;
  }
}

__global__ __launch_bounds__(256) void bn1_apply_kernel(u16* __restrict__ a1,
                                                        const float* __restrict__ S) {
  int i = (blockIdx.x * 256 + threadIdx.x) * 4;
  int cd = i / HW;
  float sc = S[cd], of = S[1024 + cd];
  ushort4 v = *(const ushort4*)(a1 + i);
  ushort4 r;
  r.x = f2bf(fmaxf(bf2f(v.x) * sc + of, 0.f));
  r.y = f2bf(fmaxf(bf2f(v.y) * sc + of, 0.f));
  r.z = f2bf(fmaxf(bf2f(v.z) * sc + of, 0.f));
  r.w = f2bf(fmaxf(bf2f(v.w) * sc + of, 0.f));
  *(ushort4*)(a1 + i) = r;
}

// conv3d 3x3x3 pad1, stats only (sum/sumsq per output channel), nothing stored.
// Identical body to the proven build EXCEPT: (1) co-grouped bid mapping so the
// 32 blocks sharing a spatial tile are co-resident (L2 reuse); (2) row loads
// vectorized: aligned ushort4/float4 for r[1..4] + 2 edge scalars.
__global__ __launch_bounds__(256) void conv_stats_kernel(const void* __restrict__ in,
                                                         const float* __restrict__ wt, int nci,
                                                         int force_bf, const int* __restrict__ flagp,
                                                         float* __restrict__ sum,
                                                         float* __restrict__ sq) {
  const int bf = force_bf ? 1 : flagp[0];
  const int bid = blockIdx.x;
  const int co = bid & 31;        // co innermost: tile shared across 32 co
  const int rem = bid >> 5;
  const int d = rem / 20;
  const int p = (rem % 20) * 256 + threadIdx.x;
  const int y = p / 40;
  const int x0 = (p % 40) * 4;

  float a0 = 0.f, a1v = 0.f, a2 = 0.f, a3 = 0.f;
  for (int ci = 0; ci < nci; ci++) {
#pragma unroll
    for (int kd = 0; kd < 3; kd++) {
      int dd = d - 1 + kd;
      if ((unsigned)dd >= (unsigned)D) continue;
      const int base = ci * DHW + dd * HW;
#pragma unroll
      for (int ky = 0; ky < 3; ky++) {
        int yy = y - 1 + ky;
        if ((unsigned)yy >= (unsigned)H) continue;
        const int rbase = base + yy * W;
        float r[6];
        if (bf) {
          ushort4 v4 = *(const ushort4*)((const u16*)in + rbase + x0);
          r[1] = bf2f(v4.x); r[2] = bf2f(v4.y); r[3] = bf2f(v4.z); r[4] = bf2f(v4.w);
        } else {
          float4 v4 = *(const float4*)((const float*)in + rbase + x0);
          r[1] = v4.x; r[2] = v4.y; r[3] = v4.z; r[4] = v4.w;
        }
        r[0] = (x0 > 0) ? ldin(in, rbase + x0 - 1, bf) : 0.f;
        r[5] = (x0 + 4 < W) ? ldin(in, rbase + x0 + 4, bf) : 0.f;
        const float* wp = wt + (((co * nci + ci) * 3 + kd) * 3 + ky) * 3;
        float w0 = wp[0], w1 = wp[1], w2 = wp[2];
        a0 += r[0] * w0 + r[1] * w1 + r[2] * w2;
        a1v += r[1] * w0 + r[2] * w1 + r[3] * w2;
        a2 += r[2] * w0 + r[3] * w1 + r[4] * w2;
        a3 += r[3] * w0 + r[4] * w1 + r[5] * w2;
      }
    }
  }
  float ps = a0 + a1v + a2 + a3;
  float pq = a0 * a0 + a1v * a1v + a2 * a2 + a3 * a3;
  __shared__ float sh[512];
  sh[threadIdx.x] = ps;
  sh[256 + threadIdx.x] = pq;
  __syncthreads();
  for (int s = 128; s > 0; s >>= 1) {
    if (threadIdx.x < (unsigned)s) {
      sh[threadIdx.x] += sh[threadIdx.x + s];
      sh[256 + threadIdx.x] += sh[256 + threadIdx.x + s];
    }
    __syncthreads();
  }
  if (threadIdx.x == 0) {
    atomicAdd(&sum[co], sh[0]);
    atomicAdd(&sq[co], sh[256]);
  }
}

__global__ void bn3_final_kernel(float* __restrict__ S, const float* __restrict__ g2f,
                                 const float* __restrict__ b2f, const float* __restrict__ gdf,
                                 const float* __restrict__ bdf) {
  int t = threadIdx.x;  // 64 threads
  if (t < 32) {
    float mean = S[2048 + t] / (float)DHW;
    float var = S[2080 + t] / (float)DHW - mean * mean;
    float sc = g2f[t] * rsqrtf(var + EPS);
    S[2176 + t] = sc;
    S[2208 + t] = b2f[t] - mean * sc;
  } else {
    int c = t - 32;
    float mean = S[2112 + c] / (float)DHW;
    float var = S[2144 + c] / (float)DHW - mean * mean;
    float sc = gdf[c] * rsqrtf(var + EPS);
    S[2240 + c] = sc;
    S[2272 + c] = bdf[c] - mean * sc;
  }
}

// recompute both convs, fuse BN3 + add + relu, write d_out.
// Same two surgical edits as conv_stats; otherwise identical to proven build.
__global__ __launch_bounds__(256) void final_conv_kernel(const u16* __restrict__ a1,
                                                         const void* __restrict__ x,
                                                         const float* __restrict__ w2f,
                                                         const float* __restrict__ wdf,
                                                         const float* __restrict__ S,
                                                         const int* __restrict__ flagp,
                                                         void* __restrict__ out) {
  const int bf = flagp[0];
  const int bid = blockIdx.x;
  const int co = bid & 31;
  const int rem = bid >> 5;
  const int d = rem / 20;
  const int p = (rem % 20) * 256 + threadIdx.x;
  const int y = p / 40;
  const int x0 = (p % 40) * 4;

  float a0 = 0.f, a1v = 0.f, a2 = 0.f, a3 = 0.f;  // main conv (from a1, 32 ci)
  for (int ci = 0; ci < COUT; ci++) {
#pragma unroll
    for (int kd = 0; kd < 3; kd++) {
      int dd = d - 1 + kd;
      if ((unsigned)dd >= (unsigned)D) continue;
      const int base = ci * DHW + dd * HW;
#pragma unroll
      for (int ky = 0; ky < 3; ky++) {
        int yy = y - 1 + ky;
        if ((unsigned)yy >= (unsigned)H) continue;
        const u16* row = a1 + base + yy * W;
        float r[6];
        {
          ushort4 v4 = *(const ushort4*)(row + x0);
          r[1] = bf2f(v4.x); r[2] = bf2f(v4.y); r[3] = bf2f(v4.z); r[4] = bf2f(v4.w);
        }
        r[0] = (x0 > 0) ? bf2f(row[x0 - 1]) : 0.f;
        r[5] = (x0 + 4 < W) ? bf2f(row[x0 + 4]) : 0.f;
        const float* wp = w2f + (((co * COUT + ci) * 3 + kd) * 3 + ky) * 3;
        float w0 = wp[0], w1 = wp[1], w2 = wp[2];
        a0 += r[0] * w0 + r[1] * w1 + r[2] * w2;
        a1v += r[1] * w0 + r[2] * w1 + r[3] * w2;
        a2 += r[2] * w0 + r[3] * w1 + r[4] * w2;
        a3 += r[3] * w0 + r[4] * w1 + r[5] * w2;
      }
    }
  }
  float b0 = 0.f, b1v = 0.f, b2v = 0.f, b3 = 0.f;  // identity conv (from x, 16 ci)
  for (int ci = 0; ci < CIN; ci++) {
#pragma unroll
    for (int kd = 0; kd < 3; kd++) {
      int dd = d - 1 + kd;
      if ((unsigned)dd >= (unsigned)D) continue;
      const int base = ci * DHW + dd * HW;
#pragma unroll
      for (int ky = 0; ky < 3; ky++) {
        int yy = y - 1 + ky;
        if ((unsigned)yy >= (unsigned)H) continue;
        const int rbase = base + yy * W;
        float r[6];
        if (bf) {
          ushort4 v4 = *(const ushort4*)((const u16*)x + rbase + x0);
          r[1] = bf2f(v4.x); r[2] = bf2f(v4.y); r[3] = bf2f(v4.z); r[4] = bf2f(v4.w);
        } else {
          float4 v4 = *(const float4*)((const float*)x + rbase + x0);
          r[1] = v4.x; r[2] = v4.y; r[3] = v4.z; r[4] = v4.w;
        }
        r[0] = (x0 > 0) ? ldin(x, rbase + x0 - 1, bf) : 0.f;
        r[5] = (x0 + 4 < W) ? ldin(x, rbase + x0 + 4, bf) : 0.f;
        const float* wp = wdf + (((co * CIN + ci) * 3 + kd) * 3 + ky) * 3;
        float w0 = wp[0], w1 = wp[1], w2 = wp[2];
        b0 += r[0] * w0 + r[1] * w1 + r[2] * w2;
        b1v += r[1] * w0 + r[2] * w1 + r[3] * w2;
        b2v += r[2] * w0 + r[3] * w1 + r[4] * w2;
        b3 += r[3] * w0 + r[4] * w1 + r[5] * w2;
      }
    }
  }

  float s2 = S[2176 + co], o2 = S[2208 + co];
  float sd = S[2240 + co], od = S[2272 + co];
  float r0 = fmaxf(a0 * s2 + o2 + b0 * sd + od, 0.f);
  float r1 = fmaxf(a1v * s2 + o2 + b1v * sd + od, 0.f);
  float r2 = fmaxf(a2 * s2 + o2 + b2v * sd + od, 0.f);
  float r3 = fmaxf(a3 * s2 + o2 + b3 * sd + od, 0.f);
  int oi = co * DHW + d * HW + y * W + x0;
  if (bf) {
    ushort4 st;
    st.x = f2bf(r0);
    st.y = f2bf(r1);
    st.z = f2bf(r2);
    st.w = f2bf(r3);
    *(ushort4*)((u16*)out + oi) = st;
  } else {
    float4 st;
    st.x = r0;
    st.y = r1;
    st.z = r2;
    st.w = r3;
    *(float4*)((float*)out + oi) = st;
  }
}

extern "C" void kernel_launch(void* const* d_in, const int* in_sizes, int n_in,
                              void* d_out, int out_size, void* d_ws, size_t ws_size,
                              hipStream_t stream) {
  const void* x = d_in[0];
  const void* f = d_in[1];

  char* ws = (char*)d_ws;
  float* S = (float*)ws;
  int* flag = (int*)ws + FLAG_SLOT;
  float* WF = (float*)(ws + WF_OFF);
  u16* a1 = (u16*)(ws + A1_OFF);

  zero_kernel<<<16, 256, 0, stream>>>(S);
  sniff_kernel<<<1, 256, 0, stream>>>((const u16*)x, flag);

  // inputs: x,f,w_off,w_reg,g1,b1,w2,g2,b2,wd,gd,bd
  const int cvt_n[10] = {2592, 4608, 27648, 13824, 32, 32, 32, 32, 32, 32};
  const int cvt_off[10] = {WOFF_O, WREG_O, W2_O, WD_O, G1_O, B1_O, G2_O, B2_O, GD_O, BD_O};
  const int src_idx[10] = {2, 3, 6, 9, 4, 5, 7, 8, 10, 11};
  for (int k = 0; k < 10; k++) {
    cvt_kernel<<<(cvt_n[k] + 255) / 256, 256, 0, stream>>>(d_in[src_idx[k]], WF + cvt_off[k],
                                                           cvt_n[k], flag);
  }

  deform_kernel<<<D * (HW / 256), 256, 0, stream>>>(x, f, WF + WOFF_O, WF + WREG_O, a1, flag);

  bn1_stats_kernel<<<COUT * D, 256, 0, stream>>>(a1, WF + G1_O, WF + B1_O, S);
  bn1_apply_kernel<<<NOUT / 1024, 256, 0, stream>>>(a1, S);

  conv_stats_kernel<<<COUT * D * 20, 256, 0, stream>>>(a1, WF + W2_O, COUT, 1, flag, S + 2048,
                                                       S + 2080);
  conv_stats_kernel<<<COUT * D * 20, 256, 0, stream>>>(x, WF + WD_O, CIN, 0, flag, S + 2112,
                                                       S + 2144);
  bn3_final_kernel<<<1, 64, 0, stream>>>(S, WF + G2_O, WF + B2_O, WF + GD_O, WF + BD_O);

  final_conv_kernel<<<COUT * D * 20, 256, 0, stream>>>(a1, x, WF + W2_O, WF + WD_O, S, flag,
                                                       d_out);
}